// Round 1
// baseline (1643.172 us; speedup 1.0000x reference)
//
#include <hip/hip_runtime.h>
#include <cstdint>
#include <cstddef>

#define BATCH 2
#define SEQ   256
#define DIM   512
#define NN    512
#define MM    16
#define NTICK 4
#define NSA   256
#define NSO   512
#define NHEAD 8
#define HDIM  64
#define VOCAB 32000
#define BS    (BATCH*SEQ)   // 512

typedef __bf16 bf16;
typedef bf16  bf16x4  __attribute__((ext_vector_type(4)));
typedef bf16  bf16x8v __attribute__((ext_vector_type(8)));
typedef float f32x4   __attribute__((ext_vector_type(4)));

// ---------------------------------------------------------------- embedding
__global__ __launch_bounds__(128) void embed_kernel(const int* __restrict__ x,
    const float* __restrict__ tok, const float* __restrict__ pos, float* __restrict__ out){
  int row = blockIdx.x;               // b*SEQ + s
  int s = row & (SEQ-1);
  int token = x[row];
  const float4* tr = (const float4*)(tok + (size_t)token*DIM);
  const float4* pr = (const float4*)(pos + (size_t)s*DIM);
  float4* orow = (float4*)(out + (size_t)row*DIM);
  for (int i = threadIdx.x; i < DIM/4; i += blockDim.x){
    float4 a = tr[i], b = pr[i];
    float4 o; o.x=a.x+b.x; o.y=a.y+b.y; o.z=a.z+b.z; o.w=a.w+b.w;
    orow[i] = o;
  }
}

// ---------------------------------------------------------------- LayerNorm over 512
__global__ __launch_bounds__(256) void ln512_kernel(const float* __restrict__ in,
    const float* __restrict__ g, const float* __restrict__ b, float* __restrict__ out){
  int row = blockIdx.x, tid = threadIdx.x;
  const float* xr = in + (size_t)row*512;
  float v0 = xr[tid], v1 = xr[tid+256];
  float s = v0+v1, ss = v0*v0+v1*v1;
  #pragma unroll
  for (int o = 32; o > 0; o >>= 1){ s += __shfl_down(s, o); ss += __shfl_down(ss, o); }
  __shared__ float rs[4], rss[4];
  __shared__ float smean, sinv;
  int wid = tid >> 6, lane = tid & 63;
  if (lane == 0){ rs[wid] = s; rss[wid] = ss; }
  __syncthreads();
  if (tid == 0){
    float S = rs[0]+rs[1]+rs[2]+rs[3];
    float SS = rss[0]+rss[1]+rss[2]+rss[3];
    float m = S * (1.0f/512.0f);
    float var = SS * (1.0f/512.0f) - m*m;
    smean = m; sinv = 1.0f/sqrtf(var + 1e-5f);
  }
  __syncthreads();
  float m = smean, inv = sinv;
  out[(size_t)row*512 + tid]       = (v0-m)*inv*g[tid]     + b[tid];
  out[(size_t)row*512 + tid + 256] = (v1-m)*inv*g[tid+256] + b[tid+256];
}

// ---------------------------------------------------------------- GLU(1024->512) + LN
__global__ __launch_bounds__(256) void glu_ln_kernel(const float* __restrict__ y,
    const float* __restrict__ g, const float* __restrict__ beta, float* __restrict__ out){
  int row = blockIdx.x, tid = threadIdx.x;
  const float* yr = y + (size_t)row*1024;
  float a0 = yr[tid],     b0 = yr[tid+512];
  float a1 = yr[tid+256], b1 = yr[tid+768];
  float g0 = a0 / (1.0f + expf(-b0));
  float g1 = a1 / (1.0f + expf(-b1));
  float s = g0+g1, ss = g0*g0+g1*g1;
  #pragma unroll
  for (int o = 32; o > 0; o >>= 1){ s += __shfl_down(s, o); ss += __shfl_down(ss, o); }
  __shared__ float rs[4], rss[4];
  __shared__ float smean, sinv;
  int wid = tid >> 6, lane = tid & 63;
  if (lane == 0){ rs[wid] = s; rss[wid] = ss; }
  __syncthreads();
  if (tid == 0){
    float S = rs[0]+rs[1]+rs[2]+rs[3];
    float SS = rss[0]+rss[1]+rss[2]+rss[3];
    float m = S * (1.0f/512.0f);
    float var = SS * (1.0f/512.0f) - m*m;
    smean = m; sinv = 1.0f/sqrtf(var + 1e-5f);
  }
  __syncthreads();
  float m = smean, inv = sinv;
  out[(size_t)row*512 + tid]       = (g0-m)*inv*g[tid]     + beta[tid];
  out[(size_t)row*512 + tid + 256] = (g1-m)*inv*g[tid+256] + beta[tid+256];
}

// ---------------------------------------------------------------- sync accumulators
__global__ __launch_bounds__(256) void sync_kernel(const float* __restrict__ act,
    const int* __restrict__ il, const int* __restrict__ ir, const float* __restrict__ decay,
    float* __restrict__ accA, float* __restrict__ accB,
    float* __restrict__ outf, bf16* __restrict__ outb, int NS, int first){
  int i = blockIdx.x*256 + threadIdx.x;
  if (i >= BS*NS) return;
  int bs = i / NS, c = i - bs*NS;
  const float* ar = act + (size_t)bs*NN;
  float p = ar[il[c]] * ar[ir[c]];
  float A, Bv;
  if (first){ A = p; Bv = 1.0f; }
  else {
    float r = expf(-decay[c]);
    A = r*accA[i] + p;
    Bv = r*accB[i] + 1.0f;
  }
  accA[i] = A; accB[i] = Bv;
  float sy = A / sqrtf(Bv + 1e-8f);
  if (outf) outf[i] = sy;
  if (outb) outb[i] = (bf16)sy;
}

// ---------------------------------------------------------------- generic f32 GEMM
// C[M,N] = A[M,K] @ W[K,N] + bias.  BM=32 BN=64 BK=16, 128 threads, 4x4 micro.
__global__ __launch_bounds__(128) void gemm_f32(
    const float* __restrict__ A, const float* __restrict__ W,
    const float* __restrict__ bias, float* __restrict__ C,
    int Mr, int Nc, int Kd, int lda, int ldc){
  __shared__ float As[16][36];
  __shared__ float Ws[16][64];
  int tid = threadIdx.x;
  int tx = tid & 15, ty = tid >> 4;
  int bm = blockIdx.y * 32, bn = blockIdx.x * 64;
  float acc[4][4] = {};
  int lm = tid >> 2, lkq = tid & 3;
  int wn4 = tid & 15, wkr = tid >> 4;
  for (int k0 = 0; k0 < Kd; k0 += 16){
    float4 a4 = *(const float4*)(A + (size_t)(bm+lm)*lda + k0 + lkq*4);
    float4 w0 = *(const float4*)(W + (size_t)(k0+wkr)*Nc + bn + wn4*4);
    float4 w1 = *(const float4*)(W + (size_t)(k0+wkr+8)*Nc + bn + wn4*4);
    As[lkq*4+0][lm] = a4.x; As[lkq*4+1][lm] = a4.y;
    As[lkq*4+2][lm] = a4.z; As[lkq*4+3][lm] = a4.w;
    *(float4*)&Ws[wkr][wn4*4]   = w0;
    *(float4*)&Ws[wkr+8][wn4*4] = w1;
    __syncthreads();
    #pragma unroll
    for (int kk = 0; kk < 16; kk++){
      float4 av = *(const float4*)&As[kk][ty*4];
      float4 wv = *(const float4*)&Ws[kk][tx*4];
      float ar[4] = {av.x, av.y, av.z, av.w};
      float wr[4] = {wv.x, wv.y, wv.z, wv.w};
      #pragma unroll
      for (int i = 0; i < 4; i++)
        #pragma unroll
        for (int j = 0; j < 4; j++)
          acc[i][j] = fmaf(ar[i], wr[j], acc[i][j]);
    }
    __syncthreads();
  }
  float4 b4 = {0,0,0,0};
  if (bias) b4 = *(const float4*)(bias + bn + tx*4);
  #pragma unroll
  for (int i = 0; i < 4; i++){
    int row = bm + ty*4 + i;
    float4 o;
    o.x = acc[i][0]+b4.x; o.y = acc[i][1]+b4.y;
    o.z = acc[i][2]+b4.z; o.w = acc[i][3]+b4.w;
    *(float4*)(C + (size_t)row*ldc + bn + tx*4) = o;
  }
}

// ---------------------------------------------------------------- bias vec: qbc = q_b@wq + bq
__global__ void qbc_kernel(const float* __restrict__ qb, const float* __restrict__ wq,
                           const float* __restrict__ bq, float* __restrict__ qbc){
  int j = blockIdx.x*64 + threadIdx.x;
  float s = bq[j];
  for (int k = 0; k < DIM; k++) s = fmaf(qb[k], wq[(size_t)k*DIM + j], s);
  qbc[j] = s;
}

// ---------------------------------------------------------------- attention (per b,h, 16-query tile)
__global__ __launch_bounds__(256) void attn_kernel(const float* __restrict__ qh,
    const float* __restrict__ kb, const float* __restrict__ vb, float* __restrict__ outb){
  int qt = blockIdx.x, h = blockIdx.y, b = blockIdx.z;
  __shared__ float qs[16][HDIM];
  __shared__ float sc[16][SEQ + 4];
  __shared__ float red[16][16];
  __shared__ float rowm[16], rowz[16];
  int tid = threadIdx.x;
  {
    int r = tid >> 4, c4 = tid & 15;
    *(float4*)&qs[r][c4*4] =
      *(const float4*)(qh + ((size_t)(b*SEQ + qt*16 + r))*DIM + h*HDIM + c4*4);
  }
  __syncthreads();
  {
    int kk = tid;
    const float* krow = kb + ((size_t)(b*SEQ + kk))*DIM + h*HDIM;
    float s[16] = {};
    for (int d4 = 0; d4 < HDIM/4; d4++){
      float4 k4 = *(const float4*)(krow + d4*4);
      #pragma unroll
      for (int q = 0; q < 16; q++){
        float4 q4 = *(const float4*)&qs[q][d4*4];
        s[q] += q4.x*k4.x + q4.y*k4.y + q4.z*k4.z + q4.w*k4.w;
      }
    }
    #pragma unroll
    for (int q = 0; q < 16; q++){
      int qg = qt*16 + q;
      sc[q][kk] = (kk > qg) ? -1e9f : s[q]*0.125f;  // 1/sqrt(64)
    }
  }
  __syncthreads();
  {
    int q = tid >> 4, seg = tid & 15;
    float m = -1e30f;
    for (int i = 0; i < 16; i++) m = fmaxf(m, sc[q][seg*16+i]);
    red[q][seg] = m;
  }
  __syncthreads();
  if (tid < 16){
    float m = red[tid][0];
    for (int i = 1; i < 16; i++) m = fmaxf(m, red[tid][i]);
    rowm[tid] = m;
  }
  __syncthreads();
  {
    int q = tid >> 4, seg = tid & 15;
    float m = rowm[q], z = 0.0f;
    for (int i = 0; i < 16; i++){
      float e = expf(sc[q][seg*16+i] - m);
      sc[q][seg*16+i] = e;
      z += e;
    }
    red[q][seg] = z;
  }
  __syncthreads();
  if (tid < 16){
    float z = 0.0f;
    for (int i = 0; i < 16; i++) z += red[tid][i];
    rowz[tid] = 1.0f / z;
  }
  __syncthreads();
  {
    int q = tid >> 4, dc = tid & 15;
    float inv = rowz[q];
    float ax=0, ay=0, az=0, aw=0;
    for (int kk = 0; kk < SEQ; kk++){
      float p = sc[q][kk];
      float4 v4 = *(const float4*)(vb + ((size_t)(b*SEQ + kk))*DIM + h*HDIM + dc*4);
      ax = fmaf(p, v4.x, ax); ay = fmaf(p, v4.y, ay);
      az = fmaf(p, v4.z, az); aw = fmaf(p, v4.w, aw);
    }
    float4 o; o.x=ax*inv; o.y=ay*inv; o.z=az*inv; o.w=aw*inv;
    *(float4*)(outb + ((size_t)(b*SEQ + qt*16 + q))*DIM + h*HDIM + dc*4) = o;
  }
}

// ---------------------------------------------------------------- copies
__global__ void act_init_kernel(const float* __restrict__ sa, float* __restrict__ act){
  int i = blockIdx.x*256 + threadIdx.x;   // 262144
  act[i] = sa[i & (SEQ*NN - 1)];
}
__global__ void cat_act_kernel(const float* __restrict__ act, float* __restrict__ cat){
  int i = blockIdx.x*256 + threadIdx.x;   // 262144
  int bs = i >> 9, n = i & 511;
  cat[(size_t)bs*1024 + 512 + n] = act[i];
}

// ---------------------------------------------------------------- per-neuron NLM (scalar weights)
__global__ __launch_bounds__(256) void nlm_kernel(
    const float* __restrict__ start_trace,
    const float* __restrict__ s0, const float* __restrict__ s1,
    const float* __restrict__ s2, const float* __restrict__ s3,
    const float* __restrict__ fc1w, const float* __restrict__ fc1b,
    const float* __restrict__ fc2w, const float* __restrict__ fc2b,
    const float* __restrict__ nlmT, float* __restrict__ act, int t){
  int n = blockIdx.x, b = blockIdx.y, s = threadIdx.x;
  int bs = b*SEQ + s;
  size_t sidx = (size_t)bs*NN + n;
  float tr[16];
  #pragma unroll
  for (int j = 0; j < 16; j++){
    int src = j + t + 1;
    if (src < 16){
      tr[j] = start_trace[((size_t)s*NN + n)*MM + src];
    } else {
      int k = src - 16;
      tr[j] = (k==0) ? s0[sidx] : (k==1) ? s1[sidx] : (k==2) ? s2[sidx] : s3[sidx];
    }
  }
  const float* w1 = fc1w + (size_t)n*16*256;
  const float* b1 = fc1b + (size_t)n*256;
  const float* w2 = fc2w + (size_t)n*256;
  float o0 = fc2b[n*2+0], o1 = fc2b[n*2+1];
  #pragma unroll 4
  for (int j = 0; j < 128; j++){
    float a  = b1[j];
    float bb = b1[j+128];
    #pragma unroll
    for (int m = 0; m < 16; m++){
      a  = fmaf(tr[m], w1[m*256 + j],       a);
      bb = fmaf(tr[m], w1[m*256 + j + 128], bb);
    }
    float gg = a / (1.0f + expf(-bb));
    o0 = fmaf(gg, w2[j*2+0], o0);
    o1 = fmaf(gg, w2[j*2+1], o1);
  }
  float o = o0 / (1.0f + expf(-o1));
  act[sidx] = o / nlmT[0];
}

// ---------------------------------------------------------------- vocab GEMM, 4 ticks fused (bf16 MFMA)
// C_t[512 x 32000] = sync_o_t(bf16) @ out_w + out_b ; writes float4 (t innermost) coalesced.
__global__ __launch_bounds__(256) void out_gemm(
    const bf16* __restrict__ sy0, const bf16* __restrict__ sy1,
    const bf16* __restrict__ sy2, const bf16* __restrict__ sy3,
    const float* __restrict__ Wo, const float* __restrict__ bo,
    float* __restrict__ outp){
  __shared__ bf16 BsT[128][40];       // [n][k] transposed, +8 pad
  int tid = threadIdx.x;
  int m0 = blockIdx.x * 64;           // 8 m-tiles (x-fast for L2 reuse of B)
  int n0 = blockIdx.y * 128;          // 250 n-tiles
  int wid = tid >> 6, lane = tid & 63;
  int ln = lane & 15, kq = lane >> 4;
  int mrow = m0 + wid*16 + ln;
  const bf16* sy[4] = {sy0, sy1, sy2, sy3};
  f32x4 acc[4][8];
  #pragma unroll
  for (int t = 0; t < 4; t++)
    #pragma unroll
    for (int nt = 0; nt < 8; nt++) acc[t][nt] = (f32x4){0.f,0.f,0.f,0.f};
  int snq = tid & 31, sk2 = tid >> 5;
  for (int k0 = 0; k0 < 512; k0 += 32){
    {
      const float* src = Wo + (size_t)(k0 + sk2*4)*VOCAB + n0 + snq*4;
      float4 r0 = *(const float4*)(src);
      float4 r1 = *(const float4*)(src + VOCAB);
      float4 r2 = *(const float4*)(src + 2*(size_t)VOCAB);
      float4 r3 = *(const float4*)(src + 3*(size_t)VOCAB);
      float c0[4] = {r0.x,r0.y,r0.z,r0.w};
      float c1[4] = {r1.x,r1.y,r1.z,r1.w};
      float c2[4] = {r2.x,r2.y,r2.z,r2.w};
      float c3[4] = {r3.x,r3.y,r3.z,r3.w};
      #pragma unroll
      for (int i = 0; i < 4; i++){
        bf16x4 pk;
        pk[0]=(bf16)c0[i]; pk[1]=(bf16)c1[i]; pk[2]=(bf16)c2[i]; pk[3]=(bf16)c3[i];
        *(bf16x4*)&BsT[snq*4+i][sk2*4] = pk;
      }
    }
    __syncthreads();
    bf16x8v af[4];
    #pragma unroll
    for (int t = 0; t < 4; t++)
      af[t] = *(const bf16x8v*)(sy[t] + (size_t)mrow*512 + k0 + kq*8);
    #pragma unroll
    for (int nt = 0; nt < 8; nt++){
      bf16x8v bfr = *(const bf16x8v*)&BsT[nt*16 + ln][kq*8];
      #pragma unroll
      for (int t = 0; t < 4; t++)
        acc[t][nt] = __builtin_amdgcn_mfma_f32_16x16x32_bf16(af[t], bfr, acc[t][nt], 0, 0, 0);
    }
    __syncthreads();
  }
  #pragma unroll
  for (int nt = 0; nt < 8; nt++){
    int col = n0 + nt*16 + ln;
    float bb = bo[col];
    #pragma unroll
    for (int r = 0; r < 4; r++){
      int row = m0 + wid*16 + kq*4 + r;
      float4 o;
      o.x = acc[0][nt][r] + bb;
      o.y = acc[1][nt][r] + bb;
      o.z = acc[2][nt][r] + bb;
      o.w = acc[3][nt][r] + bb;
      *(float4*)(outp + ((size_t)row*VOCAB + col)*4) = o;
    }
  }
}

// ---------------------------------------------------------------- entropy over V for 4 ticks at once
__global__ __launch_bounds__(256) void entropy_kernel(
    const float* __restrict__ preds, float* __restrict__ certs){
  int bs = blockIdx.x, tid = threadIdx.x;
  const float4* row = (const float4*)(preds + (size_t)bs*VOCAB*4);
  float m0=-1e30f, m1=-1e30f, m2=-1e30f, m3=-1e30f;
  for (int v = tid; v < VOCAB; v += 256){
    float4 x = row[v];
    m0 = fmaxf(m0, x.x); m1 = fmaxf(m1, x.y);
    m2 = fmaxf(m2, x.z); m3 = fmaxf(m3, x.w);
  }
  #pragma unroll
  for (int o = 32; o > 0; o >>= 1){
    m0 = fmaxf(m0, __shfl_down(m0, o)); m1 = fmaxf(m1, __shfl_down(m1, o));
    m2 = fmaxf(m2, __shfl_down(m2, o)); m3 = fmaxf(m3, __shfl_down(m3, o));
  }
  __shared__ float rm[4][4];
  __shared__ float fm[4];
  int wid = tid >> 6, lane = tid & 63;
  if (lane == 0){ rm[wid][0]=m0; rm[wid][1]=m1; rm[wid][2]=m2; rm[wid][3]=m3; }
  __syncthreads();
  if (tid == 0){
    #pragma unroll
    for (int t = 0; t < 4; t++)
      fm[t] = fmaxf(fmaxf(rm[0][t], rm[1][t]), fmaxf(rm[2][t], rm[3][t]));
  }
  __syncthreads();
  m0=fm[0]; m1=fm[1]; m2=fm[2]; m3=fm[3];
  float z0=0,z1=0,z2=0,z3=0, s0=0,s1=0,s2=0,s3=0;
  for (int v = tid; v < VOCAB; v += 256){
    float4 x = row[v];
    float e;
    e = expf(x.x-m0); z0 += e; s0 = fmaf(e, x.x-m0, s0);
    e = expf(x.y-m1); z1 += e; s1 = fmaf(e, x.y-m1, s1);
    e = expf(x.z-m2); z2 += e; s2 = fmaf(e, x.z-m2, s2);
    e = expf(x.w-m3); z3 += e; s3 = fmaf(e, x.w-m3, s3);
  }
  #pragma unroll
  for (int o = 32; o > 0; o >>= 1){
    z0 += __shfl_down(z0,o); z1 += __shfl_down(z1,o);
    z2 += __shfl_down(z2,o); z3 += __shfl_down(z3,o);
    s0 += __shfl_down(s0,o); s1 += __shfl_down(s1,o);
    s2 += __shfl_down(s2,o); s3 += __shfl_down(s3,o);
  }
  __shared__ float rz[4][8];
  if (lane == 0){
    rz[wid][0]=z0; rz[wid][1]=z1; rz[wid][2]=z2; rz[wid][3]=z3;
    rz[wid][4]=s0; rz[wid][5]=s1; rz[wid][6]=s2; rz[wid][7]=s3;
  }
  __syncthreads();
  if (tid == 0){
    float inv_logV = 1.0f / logf((float)VOCAB);
    #pragma unroll
    for (int t = 0; t < 4; t++){
      float Z = rz[0][t]+rz[1][t]+rz[2][t]+rz[3][t];
      float Ss = rz[0][t+4]+rz[1][t+4]+rz[2][t+4]+rz[3][t+4];
      float ent = (logf(Z) - Ss/Z) * inv_logV;
      certs[((size_t)bs*2 + 0)*4 + t] = ent;
      certs[((size_t)bs*2 + 1)*4 + t] = 1.0f - ent;
    }
  }
}

// ================================================================ host
extern "C" void kernel_launch(void* const* d_in, const int* in_sizes, int n_in,
                              void* d_out, int out_size, void* d_ws, size_t ws_size,
                              hipStream_t stream){
  const int*   x        = (const int*)  d_in[0];
  const float* tok      = (const float*)d_in[1];
  const float* pos      = (const float*)d_in[2];
  const float* ln_emb_g = (const float*)d_in[3];
  const float* ln_emb_b = (const float*)d_in[4];
  const float* kv_w     = (const float*)d_in[5];
  const float* kv_b     = (const float*)d_in[6];
  const float* kv_ln_g  = (const float*)d_in[7];
  const float* kv_ln_b  = (const float*)d_in[8];
  const float* q_w      = (const float*)d_in[9];
  const float* q_b      = (const float*)d_in[10];
  const float* wq       = (const float*)d_in[11];
  const float* bq       = (const float*)d_in[12];
  const float* wk       = (const float*)d_in[13];
  const float* bk       = (const float*)d_in[14];
  const float* wv       = (const float*)d_in[15];
  const float* bv       = (const float*)d_in[16];
  const float* ow       = (const float*)d_in[17];
  const float* ob       = (const float*)d_in[18];
  const float* syn_w    = (const float*)d_in[19];
  const float* syn_b    = (const float*)d_in[20];
  const float* syn_g    = (const float*)d_in[21];
  const float* syn_beta = (const float*)d_in[22];
  const float* fc1_w    = (const float*)d_in[23];
  const float* fc1_b    = (const float*)d_in[24];
  const float* fc2_w    = (const float*)d_in[25];
  const float* fc2_b    = (const float*)d_in[26];
  const float* nlm_T    = (const float*)d_in[27];
  const float* start_act   = (const float*)d_in[28];
  const float* start_trace = (const float*)d_in[29];
  const float* decay_a  = (const float*)d_in[30];
  const float* decay_o  = (const float*)d_in[31];
  const float* out_w    = (const float*)d_in[32];
  const float* out_b    = (const float*)d_in[33];
  const int* idx_al = (const int*)d_in[34];
  const int* idx_ar = (const int*)d_in[35];
  const int* idx_ol = (const int*)d_in[36];
  const int* idx_or = (const int*)d_in[37];

  char* wp = (char*)d_ws;
  auto alloc = [&](size_t bytes) -> void* {
    void* p = (void*)wp;
    wp += (bytes + 255) & ~(size_t)255;
    return p;
  };
  float* qwc      = (float*)alloc((size_t)256*512*4);
  float* qbc      = (float*)alloc(512*4);
  float* emb_raw  = (float*)alloc((size_t)BS*512*4);
  float* emb      = (float*)alloc((size_t)BS*512*4);
  float* kvt      = (float*)alloc((size_t)BS*512*4);
  float* kvn      = (float*)alloc((size_t)BS*512*4);
  float* kbuf     = (float*)alloc((size_t)BS*512*4);
  float* vbuf     = (float*)alloc((size_t)BS*512*4);
  float* act      = (float*)alloc((size_t)BS*512*4);
  float* aaB      = (float*)alloc((size_t)BS*256*4);
  float* baB      = (float*)alloc((size_t)BS*256*4);
  float* aoB      = (float*)alloc((size_t)BS*512*4);
  float* boB      = (float*)alloc((size_t)BS*512*4);
  float* sync_a   = (float*)alloc((size_t)BS*256*4);
  float* qh       = (float*)alloc((size_t)BS*512*4);
  float* attn_raw = (float*)alloc((size_t)BS*512*4);
  float* catb     = (float*)alloc((size_t)BS*1024*4);
  float* syn_y    = (float*)alloc((size_t)BS*1024*4);
  float* states[NTICK];
  for (int t = 0; t < NTICK; t++) states[t] = (float*)alloc((size_t)BS*512*4);
  bf16* syob[NTICK];
  for (int t = 0; t < NTICK; t++) syob[t] = (bf16*)alloc((size_t)BS*512*2);

  float* preds = (float*)d_out;
  float* certs = (float*)d_out + (size_t)BS*VOCAB*NTICK;

  // ---- pre
  embed_kernel<<<BS, 128, 0, stream>>>(x, tok, pos, emb_raw);
  ln512_kernel<<<BS, 256, 0, stream>>>(emb_raw, ln_emb_g, ln_emb_b, emb);
  gemm_f32<<<dim3(512/64, 512/32), 128, 0, stream>>>(emb, kv_w, kv_b, kvt, 512,512,512, 512,512);
  ln512_kernel<<<BS, 256, 0, stream>>>(kvt, kv_ln_g, kv_ln_b, kvn);
  gemm_f32<<<dim3(512/64, 512/32), 128, 0, stream>>>(kvn, wk, bk, kbuf, 512,512,512, 512,512);
  gemm_f32<<<dim3(512/64, 512/32), 128, 0, stream>>>(kvn, wv, bv, vbuf, 512,512,512, 512,512);
  gemm_f32<<<dim3(512/64, 256/32), 128, 0, stream>>>(q_w, wq, nullptr, qwc, 256,512,512, 512,512);
  qbc_kernel<<<8, 64, 0, stream>>>(q_b, wq, bq, qbc);
  act_init_kernel<<<(BS*NN)/256, 256, 0, stream>>>(start_act, act);

  // ---- ticks
  for (int t = 0; t < NTICK; t++){
    sync_kernel<<<(BS*NSA)/256, 256, 0, stream>>>(act, idx_al, idx_ar, decay_a,
        aaB, baB, sync_a, nullptr, NSA, t==0);
    gemm_f32<<<dim3(512/64, 512/32), 128, 0, stream>>>(sync_a, qwc, qbc, qh, 512,512,256, 256,512);
    attn_kernel<<<dim3(16, NHEAD, BATCH), 256, 0, stream>>>(qh, kbuf, vbuf, attn_raw);
    gemm_f32<<<dim3(512/64, 512/32), 128, 0, stream>>>(attn_raw, ow, ob, catb, 512,512,512, 512,1024);
    cat_act_kernel<<<(BS*NN)/256, 256, 0, stream>>>(act, catb);
    gemm_f32<<<dim3(1024/64, 512/32), 128, 0, stream>>>(catb, syn_w, syn_b, syn_y, 512,1024,1024, 1024,1024);
    glu_ln_kernel<<<BS, 256, 0, stream>>>(syn_y, syn_g, syn_beta, states[t]);
    nlm_kernel<<<dim3(NN, BATCH), 256, 0, stream>>>(start_trace,
        states[0], states[1], states[2], states[3],
        fc1_w, fc1_b, fc2_w, fc2_b, nlm_T, act, t);
    sync_kernel<<<(BS*NSO)/256, 256, 0, stream>>>(act, idx_ol, idx_or, decay_o,
        aoB, boB, nullptr, syob[t], NSO, t==0);
  }

  // ---- output projection (all 4 ticks fused, coalesced float4 stores) + entropy
  out_gemm<<<dim3(BS/64, VOCAB/128), 256, 0, stream>>>(
      syob[0], syob[1], syob[2], syob[3], out_w, out_b, preds);
  entropy_kernel<<<BS, 256, 0, stream>>>(preds, certs);
}

// Round 2
// 1563.955 us; speedup vs baseline: 1.0507x; 1.0507x over previous
//
#include <hip/hip_runtime.h>
#include <cstdint>
#include <cstddef>

#define BATCH 2
#define SEQ   256
#define DIM   512
#define NN    512
#define MM    16
#define NTICK 4
#define NSA   256
#define NSO   512
#define NHEAD 8
#define HDIM  64
#define VOCAB 32000
#define BS    (BATCH*SEQ)   // 512
#define NBLK  250           // VOCAB/128 partial blocks

typedef __bf16 bf16;
typedef bf16  bf16x4  __attribute__((ext_vector_type(4)));
typedef bf16  bf16x8v __attribute__((ext_vector_type(8)));
typedef float f32x4   __attribute__((ext_vector_type(4)));

// ---------------------------------------------------------------- embedding
__global__ __launch_bounds__(128) void embed_kernel(const int* __restrict__ x,
    const float* __restrict__ tok, const float* __restrict__ pos, float* __restrict__ out){
  int row = blockIdx.x;               // b*SEQ + s
  int s = row & (SEQ-1);
  int token = x[row];
  const float4* tr = (const float4*)(tok + (size_t)token*DIM);
  const float4* pr = (const float4*)(pos + (size_t)s*DIM);
  float4* orow = (float4*)(out + (size_t)row*DIM);
  for (int i = threadIdx.x; i < DIM/4; i += blockDim.x){
    float4 a = tr[i], b = pr[i];
    float4 o; o.x=a.x+b.x; o.y=a.y+b.y; o.z=a.z+b.z; o.w=a.w+b.w;
    orow[i] = o;
  }
}

// ---------------------------------------------------------------- LayerNorm over 512
__global__ __launch_bounds__(256) void ln512_kernel(const float* __restrict__ in,
    const float* __restrict__ g, const float* __restrict__ b, float* __restrict__ out){
  int row = blockIdx.x, tid = threadIdx.x;
  const float* xr = in + (size_t)row*512;
  float v0 = xr[tid], v1 = xr[tid+256];
  float s = v0+v1, ss = v0*v0+v1*v1;
  #pragma unroll
  for (int o = 32; o > 0; o >>= 1){ s += __shfl_down(s, o); ss += __shfl_down(ss, o); }
  __shared__ float rs[4], rss[4];
  __shared__ float smean, sinv;
  int wid = tid >> 6, lane = tid & 63;
  if (lane == 0){ rs[wid] = s; rss[wid] = ss; }
  __syncthreads();
  if (tid == 0){
    float S = rs[0]+rs[1]+rs[2]+rs[3];
    float SS = rss[0]+rss[1]+rss[2]+rss[3];
    float m = S * (1.0f/512.0f);
    float var = SS * (1.0f/512.0f) - m*m;
    smean = m; sinv = 1.0f/sqrtf(var + 1e-5f);
  }
  __syncthreads();
  float m = smean, inv = sinv;
  out[(size_t)row*512 + tid]       = (v0-m)*inv*g[tid]     + b[tid];
  out[(size_t)row*512 + tid + 256] = (v1-m)*inv*g[tid+256] + b[tid+256];
}

// ---------------------------------------------------------------- GLU(1024->512) + LN
__global__ __launch_bounds__(256) void glu_ln_kernel(const float* __restrict__ y,
    const float* __restrict__ g, const float* __restrict__ beta, float* __restrict__ out){
  int row = blockIdx.x, tid = threadIdx.x;
  const float* yr = y + (size_t)row*1024;
  float a0 = yr[tid],     b0 = yr[tid+512];
  float a1 = yr[tid+256], b1 = yr[tid+768];
  float g0 = a0 / (1.0f + expf(-b0));
  float g1 = a1 / (1.0f + expf(-b1));
  float s = g0+g1, ss = g0*g0+g1*g1;
  #pragma unroll
  for (int o = 32; o > 0; o >>= 1){ s += __shfl_down(s, o); ss += __shfl_down(ss, o); }
  __shared__ float rs[4], rss[4];
  __shared__ float smean, sinv;
  int wid = tid >> 6, lane = tid & 63;
  if (lane == 0){ rs[wid] = s; rss[wid] = ss; }
  __syncthreads();
  if (tid == 0){
    float S = rs[0]+rs[1]+rs[2]+rs[3];
    float SS = rss[0]+rss[1]+rss[2]+rss[3];
    float m = S * (1.0f/512.0f);
    float var = SS * (1.0f/512.0f) - m*m;
    smean = m; sinv = 1.0f/sqrtf(var + 1e-5f);
  }
  __syncthreads();
  float m = smean, inv = sinv;
  out[(size_t)row*512 + tid]       = (g0-m)*inv*g[tid]     + beta[tid];
  out[(size_t)row*512 + tid + 256] = (g1-m)*inv*g[tid+256] + beta[tid+256];
}

// ---------------------------------------------------------------- sync accumulators
__global__ __launch_bounds__(256) void sync_kernel(const float* __restrict__ act,
    const int* __restrict__ il, const int* __restrict__ ir, const float* __restrict__ decay,
    float* __restrict__ accA, float* __restrict__ accB,
    float* __restrict__ outf, bf16* __restrict__ outb, int NS, int first){
  int i = blockIdx.x*256 + threadIdx.x;
  if (i >= BS*NS) return;
  int bs = i / NS, c = i - bs*NS;
  const float* ar = act + (size_t)bs*NN;
  float p = ar[il[c]] * ar[ir[c]];
  float A, Bv;
  if (first){ A = p; Bv = 1.0f; }
  else {
    float r = expf(-decay[c]);
    A = r*accA[i] + p;
    Bv = r*accB[i] + 1.0f;
  }
  accA[i] = A; accB[i] = Bv;
  float sy = A / sqrtf(Bv + 1e-8f);
  if (outf) outf[i] = sy;
  if (outb) outb[i] = (bf16)sy;
}

// ---------------------------------------------------------------- split+transpose weight
// W f32 [K][N] -> hiT,loT bf16 [N][K].  loT may be null (hi-only, for out_w).
__global__ __launch_bounds__(256) void split_t(const float* __restrict__ W,
    bf16* __restrict__ hiT, bf16* __restrict__ loT, int K, int N){
  __shared__ float t[32][33];
  int n0 = blockIdx.x*32, k0 = blockIdx.y*32;
  int tid = threadIdx.x;
  int r = tid >> 3, c4 = (tid & 7)*4;
  float4 v = *(const float4*)(W + (size_t)(k0+r)*N + n0 + c4);
  t[r][c4+0]=v.x; t[r][c4+1]=v.y; t[r][c4+2]=v.z; t[r][c4+3]=v.w;
  __syncthreads();
  bf16x4 hi, lo;
  #pragma unroll
  for (int j = 0; j < 4; j++){
    float a = t[c4+j][r];
    bf16 h = (bf16)a;
    hi[j] = h;
    lo[j] = (bf16)(a - (float)h);
  }
  *(bf16x4*)(hiT + (size_t)(n0+r)*K + k0 + c4) = hi;
  if (loT) *(bf16x4*)(loT + (size_t)(n0+r)*K + k0 + c4) = lo;
}

// ---------------------------------------------------------------- bf16x3 MFMA GEMM
// C[M,N] = A(f32)[M,K] @ W + bias, with W pre-split WhT/WlT bf16 [N][K].
// 1 wave/block: 16 m-rows x 64 n-cols.  grid = (N/64, M/16).
__global__ __launch_bounds__(64) void gemm_x3(
    const float* __restrict__ A, const bf16* __restrict__ WhT,
    const bf16* __restrict__ WlT, const float* __restrict__ bias,
    float* __restrict__ C, int K, int lda, int ldc){
  int n0 = blockIdx.x * 64, m0 = blockIdx.y * 16;
  int lane = threadIdx.x;
  int ln = lane & 15, kq = lane >> 4;
  f32x4 acc[4];
  #pragma unroll
  for (int nf = 0; nf < 4; nf++) acc[nf] = (f32x4){0.f,0.f,0.f,0.f};
  const float* arow = A + (size_t)(m0 + ln)*lda + kq*8;
  const bf16* w0h = WhT + (size_t)(n0 + ln)*K + kq*8;
  const bf16* w0l = WlT + (size_t)(n0 + ln)*K + kq*8;
  size_t nstep = (size_t)16*K;
  for (int k0 = 0; k0 < K; k0 += 32){
    float4 a0 = *(const float4*)(arow + k0);
    float4 a1 = *(const float4*)(arow + k0 + 4);
    float av[8] = {a0.x,a0.y,a0.z,a0.w,a1.x,a1.y,a1.z,a1.w};
    bf16x8v ahi, alo;
    #pragma unroll
    for (int j = 0; j < 8; j++){
      bf16 h = (bf16)av[j];
      ahi[j] = h;
      alo[j] = (bf16)(av[j] - (float)h);
    }
    #pragma unroll
    for (int nf = 0; nf < 4; nf++){
      bf16x8v bh = *(const bf16x8v*)(w0h + nf*nstep + k0);
      bf16x8v bl = *(const bf16x8v*)(w0l + nf*nstep + k0);
      acc[nf] = __builtin_amdgcn_mfma_f32_16x16x32_bf16(ahi, bh, acc[nf], 0,0,0);
      acc[nf] = __builtin_amdgcn_mfma_f32_16x16x32_bf16(alo, bh, acc[nf], 0,0,0);
      acc[nf] = __builtin_amdgcn_mfma_f32_16x16x32_bf16(ahi, bl, acc[nf], 0,0,0);
    }
  }
  #pragma unroll
  for (int nf = 0; nf < 4; nf++){
    int col = n0 + nf*16 + ln;
    float bb = bias ? bias[col] : 0.0f;
    #pragma unroll
    for (int r = 0; r < 4; r++)
      C[(size_t)(m0 + kq*4 + r)*ldc + col] = acc[nf][r] + bb;
  }
}

// ---------------------------------------------------------------- bias vec: qbc = q_b@wq + bq
__global__ void qbc_kernel(const float* __restrict__ qb, const float* __restrict__ wq,
                           const float* __restrict__ bq, float* __restrict__ qbc){
  int j = blockIdx.x*64 + threadIdx.x;
  float s = bq[j];
  for (int k = 0; k < DIM; k++) s = fmaf(qb[k], wq[(size_t)k*DIM + j], s);
  qbc[j] = s;
}

// ---------------------------------------------------------------- attention (per b,h, 16-query tile)
__global__ __launch_bounds__(256) void attn_kernel(const float* __restrict__ qh,
    const float* __restrict__ kb, const float* __restrict__ vb, float* __restrict__ outb){
  int qt = blockIdx.x, h = blockIdx.y, b = blockIdx.z;
  __shared__ float qs[16][HDIM];
  __shared__ float sc[16][SEQ + 4];
  __shared__ float red[16][16];
  __shared__ float rowm[16], rowz[16];
  int tid = threadIdx.x;
  {
    int r = tid >> 4, c4 = tid & 15;
    *(float4*)&qs[r][c4*4] =
      *(const float4*)(qh + ((size_t)(b*SEQ + qt*16 + r))*DIM + h*HDIM + c4*4);
  }
  __syncthreads();
  {
    int kk = tid;
    const float* krow = kb + ((size_t)(b*SEQ + kk))*DIM + h*HDIM;
    float s[16] = {};
    for (int d4 = 0; d4 < HDIM/4; d4++){
      float4 k4 = *(const float4*)(krow + d4*4);
      #pragma unroll
      for (int q = 0; q < 16; q++){
        float4 q4 = *(const float4*)&qs[q][d4*4];
        s[q] += q4.x*k4.x + q4.y*k4.y + q4.z*k4.z + q4.w*k4.w;
      }
    }
    #pragma unroll
    for (int q = 0; q < 16; q++){
      int qg = qt*16 + q;
      sc[q][kk] = (kk > qg) ? -1e9f : s[q]*0.125f;
    }
  }
  __syncthreads();
  {
    int q = tid >> 4, seg = tid & 15;
    float m = -1e30f;
    for (int i = 0; i < 16; i++) m = fmaxf(m, sc[q][seg*16+i]);
    red[q][seg] = m;
  }
  __syncthreads();
  if (tid < 16){
    float m = red[tid][0];
    for (int i = 1; i < 16; i++) m = fmaxf(m, red[tid][i]);
    rowm[tid] = m;
  }
  __syncthreads();
  {
    int q = tid >> 4, seg = tid & 15;
    float m = rowm[q], z = 0.0f;
    for (int i = 0; i < 16; i++){
      float e = expf(sc[q][seg*16+i] - m);
      sc[q][seg*16+i] = e;
      z += e;
    }
    red[q][seg] = z;
  }
  __syncthreads();
  if (tid < 16){
    float z = 0.0f;
    for (int i = 0; i < 16; i++) z += red[tid][i];
    rowz[tid] = 1.0f / z;
  }
  __syncthreads();
  {
    int q = tid >> 4, dc = tid & 15;
    float inv = rowz[q];
    float ax=0, ay=0, az=0, aw=0;
    for (int kk = 0; kk < SEQ; kk++){
      float p = sc[q][kk];
      float4 v4 = *(const float4*)(vb + ((size_t)(b*SEQ + kk))*DIM + h*HDIM + dc*4);
      ax = fmaf(p, v4.x, ax); ay = fmaf(p, v4.y, ay);
      az = fmaf(p, v4.z, az); aw = fmaf(p, v4.w, aw);
    }
    float4 o; o.x=ax*inv; o.y=ay*inv; o.z=az*inv; o.w=aw*inv;
    *(float4*)(outb + ((size_t)(b*SEQ + qt*16 + q))*DIM + h*HDIM + dc*4) = o;
  }
}

// ---------------------------------------------------------------- copies
__global__ void act_init_kernel(const float* __restrict__ sa, float* __restrict__ act){
  int i = blockIdx.x*256 + threadIdx.x;
  act[i] = sa[i & (SEQ*NN - 1)];
}
__global__ void cat_act_kernel(const float* __restrict__ act, float* __restrict__ cat){
  int i = blockIdx.x*256 + threadIdx.x;
  int bs = i >> 9, n = i & 511;
  cat[(size_t)bs*1024 + 512 + n] = act[i];
}

// ---------------------------------------------------------------- per-neuron NLM
__global__ __launch_bounds__(256) void nlm_kernel(
    const float* __restrict__ start_trace,
    const float* __restrict__ s0, const float* __restrict__ s1,
    const float* __restrict__ s2, const float* __restrict__ s3,
    const float* __restrict__ fc1w, const float* __restrict__ fc1b,
    const float* __restrict__ fc2w, const float* __restrict__ fc2b,
    const float* __restrict__ nlmT, float* __restrict__ act, int t){
  int n = blockIdx.x, b = blockIdx.y, s = threadIdx.x;
  int bs = b*SEQ + s;
  size_t sidx = (size_t)bs*NN + n;
  float tr[16];
  #pragma unroll
  for (int j = 0; j < 16; j++){
    int src = j + t + 1;
    if (src < 16){
      tr[j] = start_trace[((size_t)s*NN + n)*MM + src];
    } else {
      int k = src - 16;
      tr[j] = (k==0) ? s0[sidx] : (k==1) ? s1[sidx] : (k==2) ? s2[sidx] : s3[sidx];
    }
  }
  const float* w1 = fc1w + (size_t)n*16*256;
  const float* b1 = fc1b + (size_t)n*256;
  const float* w2 = fc2w + (size_t)n*256;
  float o0 = fc2b[n*2+0], o1 = fc2b[n*2+1];
  #pragma unroll 4
  for (int j = 0; j < 128; j++){
    float a  = b1[j];
    float bb = b1[j+128];
    #pragma unroll
    for (int m = 0; m < 16; m++){
      a  = fmaf(tr[m], w1[m*256 + j],       a);
      bb = fmaf(tr[m], w1[m*256 + j + 128], bb);
    }
    float gg = a / (1.0f + expf(-bb));
    o0 = fmaf(gg, w2[j*2+0], o0);
    o1 = fmaf(gg, w2[j*2+1], o1);
  }
  float o = o0 / (1.0f + expf(-o1));
  act[sidx] = o / nlmT[0];
}

// ---------------------------------------------------------------- vocab GEMM v2 + fused entropy partials
// preds[512 x 32000 x 4] = syob_t @ WoT^T + bo.  No LDS round-trip for operands.
// Each block: 16 m-rows x 128 n-cols, 4 waves each own 32 cols.  grid (32, 250), x fastest.
__global__ __launch_bounds__(256) void out_gemm2(
    const bf16* __restrict__ sy0, const bf16* __restrict__ sy1,
    const bf16* __restrict__ sy2, const bf16* __restrict__ sy3,
    const bf16* __restrict__ WoT, const float* __restrict__ bo,
    float* __restrict__ outp, float* __restrict__ pm,
    float* __restrict__ pz, float* __restrict__ ps){
  int m0 = blockIdx.x * 16;
  int n0 = blockIdx.y * 128;
  int tid = threadIdx.x;
  int w = tid >> 6, lane = tid & 63;
  int ln = lane & 15, kq = lane >> 4;
  int nb = n0 + w*32;
  f32x4 acc[4][2];
  #pragma unroll
  for (int t = 0; t < 4; t++){
    acc[t][0] = (f32x4){0.f,0.f,0.f,0.f};
    acc[t][1] = (f32x4){0.f,0.f,0.f,0.f};
  }
  size_t aoff = (size_t)(m0 + ln)*512 + kq*8;
  const bf16* a0p = sy0 + aoff;
  const bf16* a1p = sy1 + aoff;
  const bf16* a2p = sy2 + aoff;
  const bf16* a3p = sy3 + aoff;
  const bf16* b0p = WoT + (size_t)(nb + ln)*512 + kq*8;
  const bf16* b1p = b0p + (size_t)16*512;
  for (int k0 = 0; k0 < 512; k0 += 32){
    bf16x8v av0 = *(const bf16x8v*)(a0p + k0);
    bf16x8v av1 = *(const bf16x8v*)(a1p + k0);
    bf16x8v av2 = *(const bf16x8v*)(a2p + k0);
    bf16x8v av3 = *(const bf16x8v*)(a3p + k0);
    bf16x8v bv0 = *(const bf16x8v*)(b0p + k0);
    bf16x8v bv1 = *(const bf16x8v*)(b1p + k0);
    acc[0][0] = __builtin_amdgcn_mfma_f32_16x16x32_bf16(av0, bv0, acc[0][0], 0,0,0);
    acc[1][0] = __builtin_amdgcn_mfma_f32_16x16x32_bf16(av1, bv0, acc[1][0], 0,0,0);
    acc[2][0] = __builtin_amdgcn_mfma_f32_16x16x32_bf16(av2, bv0, acc[2][0], 0,0,0);
    acc[3][0] = __builtin_amdgcn_mfma_f32_16x16x32_bf16(av3, bv0, acc[3][0], 0,0,0);
    acc[0][1] = __builtin_amdgcn_mfma_f32_16x16x32_bf16(av0, bv1, acc[0][1], 0,0,0);
    acc[1][1] = __builtin_amdgcn_mfma_f32_16x16x32_bf16(av1, bv1, acc[1][1], 0,0,0);
    acc[2][1] = __builtin_amdgcn_mfma_f32_16x16x32_bf16(av2, bv1, acc[2][1], 0,0,0);
    acc[3][1] = __builtin_amdgcn_mfma_f32_16x16x32_bf16(av3, bv1, acc[3][1], 0,0,0);
  }
  // bias
  float bb0 = bo[nb + ln], bb1 = bo[nb + 16 + ln];
  #pragma unroll
  for (int t = 0; t < 4; t++)
    #pragma unroll
    for (int r = 0; r < 4; r++){ acc[t][0][r] += bb0; acc[t][1][r] += bb1; }
  // store preds: float4 = 4 ticks, coalesced
  #pragma unroll
  for (int r = 0; r < 4; r++){
    size_t rowoff = (size_t)(m0 + kq*4 + r)*VOCAB;
    float4 o0, o1;
    o0.x=acc[0][0][r]; o0.y=acc[1][0][r]; o0.z=acc[2][0][r]; o0.w=acc[3][0][r];
    o1.x=acc[0][1][r]; o1.y=acc[1][1][r]; o1.z=acc[2][1][r]; o1.w=acc[3][1][r];
    *(float4*)(outp + (rowoff + nb + ln)*4)      = o0;
    *(float4*)(outp + (rowoff + nb + 16 + ln)*4) = o1;
  }
  // ---- entropy partials over this block's 128 cols ----
  __shared__ float redm[4][4][16], redz[4][4][16], reds[4][4][16];
  float gm[4][4];
  #pragma unroll
  for (int t = 0; t < 4; t++)
    #pragma unroll
    for (int r = 0; r < 4; r++){
      float m = fmaxf(acc[t][0][r], acc[t][1][r]);
      #pragma unroll
      for (int o2 = 1; o2 < 16; o2 <<= 1) m = fmaxf(m, __shfl_xor(m, o2));
      gm[t][r] = m;
    }
  if (ln == 0){
    #pragma unroll
    for (int t = 0; t < 4; t++)
      #pragma unroll
      for (int r = 0; r < 4; r++) redm[w][t][kq*4+r] = gm[t][r];
  }
  __syncthreads();
  #pragma unroll
  for (int t = 0; t < 4; t++)
    #pragma unroll
    for (int r = 0; r < 4; r++){
      int row = kq*4+r;
      gm[t][r] = fmaxf(fmaxf(redm[0][t][row], redm[1][t][row]),
                       fmaxf(redm[2][t][row], redm[3][t][row]));
    }
  float zz[4][4], ssv[4][4];
  #pragma unroll
  for (int t = 0; t < 4; t++)
    #pragma unroll
    for (int r = 0; r < 4; r++){
      float v0 = acc[t][0][r] - gm[t][r];
      float v1 = acc[t][1][r] - gm[t][r];
      float e0 = expf(v0), e1 = expf(v1);
      float z = e0 + e1;
      float s = v0*e0 + v1*e1;
      #pragma unroll
      for (int o2 = 1; o2 < 16; o2 <<= 1){ z += __shfl_xor(z, o2); s += __shfl_xor(s, o2); }
      zz[t][r] = z; ssv[t][r] = s;
    }
  if (ln == 0){
    #pragma unroll
    for (int t = 0; t < 4; t++)
      #pragma unroll
      for (int r = 0; r < 4; r++){ redz[w][t][kq*4+r] = zz[t][r]; reds[w][t][kq*4+r] = ssv[t][r]; }
  }
  __syncthreads();
  if (w == 0 && ln == 0){
    #pragma unroll
    for (int t = 0; t < 4; t++)
      #pragma unroll
      for (int r = 0; r < 4; r++){
        int row = kq*4 + r;
        float Z = redz[0][t][row]+redz[1][t][row]+redz[2][t][row]+redz[3][t][row];
        float S = reds[0][t][row]+reds[1][t][row]+reds[2][t][row]+reds[3][t][row];
        size_t p = ((size_t)(m0+row)*4 + t)*NBLK + blockIdx.y;
        pm[p] = gm[t][r]; pz[p] = Z; ps[p] = S;
      }
  }
}

// ---------------------------------------------------------------- entropy finalize
__global__ __launch_bounds__(64) void ent_final(const float* __restrict__ pm,
    const float* __restrict__ pz, const float* __restrict__ ps, float* __restrict__ certs){
  int row = blockIdx.x >> 2, t = blockIdx.x & 3;
  const size_t base = ((size_t)row*4 + t)*NBLK;
  int lane = threadIdx.x;
  float M = -1e30f, Z = 0.0f, S = 0.0f;
  for (int i = lane; i < NBLK; i += 64){
    float m2 = pm[base+i], z2 = pz[base+i], s2 = ps[base+i];
    float Mn = fmaxf(M, m2);
    float e1 = expf(M - Mn), e2 = expf(m2 - Mn);
    S = (S + (M - Mn)*Z)*e1 + (s2 + (m2 - Mn)*z2)*e2;
    Z = Z*e1 + z2*e2;
    M = Mn;
  }
  #pragma unroll
  for (int o = 1; o < 64; o <<= 1){
    float m2 = __shfl_xor(M, o), z2 = __shfl_xor(Z, o), s2 = __shfl_xor(S, o);
    float Mn = fmaxf(M, m2);
    float e1 = expf(M - Mn), e2 = expf(m2 - Mn);
    S = (S + (M - Mn)*Z)*e1 + (s2 + (m2 - Mn)*z2)*e2;
    Z = Z*e1 + z2*e2;
    M = Mn;
  }
  if (lane == 0){
    float ent = (logf(Z) - S/Z) * (1.0f / logf((float)VOCAB));
    certs[((size_t)row*2 + 0)*4 + t] = ent;
    certs[((size_t)row*2 + 1)*4 + t] = 1.0f - ent;
  }
}

// ================================================================ host
extern "C" void kernel_launch(void* const* d_in, const int* in_sizes, int n_in,
                              void* d_out, int out_size, void* d_ws, size_t ws_size,
                              hipStream_t stream){
  const int*   x        = (const int*)  d_in[0];
  const float* tok      = (const float*)d_in[1];
  const float* pos      = (const float*)d_in[2];
  const float* ln_emb_g = (const float*)d_in[3];
  const float* ln_emb_b = (const float*)d_in[4];
  const float* kv_w     = (const float*)d_in[5];
  const float* kv_b     = (const float*)d_in[6];
  const float* kv_ln_g  = (const float*)d_in[7];
  const float* kv_ln_b  = (const float*)d_in[8];
  const float* q_w      = (const float*)d_in[9];
  const float* q_b      = (const float*)d_in[10];
  const float* wq       = (const float*)d_in[11];
  const float* bq       = (const float*)d_in[12];
  const float* wk       = (const float*)d_in[13];
  const float* bk       = (const float*)d_in[14];
  const float* wv       = (const float*)d_in[15];
  const float* bv       = (const float*)d_in[16];
  const float* ow       = (const float*)d_in[17];
  const float* ob       = (const float*)d_in[18];
  const float* syn_w    = (const float*)d_in[19];
  const float* syn_b    = (const float*)d_in[20];
  const float* syn_g    = (const float*)d_in[21];
  const float* syn_beta = (const float*)d_in[22];
  const float* fc1_w    = (const float*)d_in[23];
  const float* fc1_b    = (const float*)d_in[24];
  const float* fc2_w    = (const float*)d_in[25];
  const float* fc2_b    = (const float*)d_in[26];
  const float* nlm_T    = (const float*)d_in[27];
  const float* start_act   = (const float*)d_in[28];
  const float* start_trace = (const float*)d_in[29];
  const float* decay_a  = (const float*)d_in[30];
  const float* decay_o  = (const float*)d_in[31];
  const float* out_w    = (const float*)d_in[32];
  const float* out_b    = (const float*)d_in[33];
  const int* idx_al = (const int*)d_in[34];
  const int* idx_ar = (const int*)d_in[35];
  const int* idx_ol = (const int*)d_in[36];
  const int* idx_or = (const int*)d_in[37];

  char* wp = (char*)d_ws;
  auto alloc = [&](size_t bytes) -> void* {
    void* p = (void*)wp;
    wp += (bytes + 255) & ~(size_t)255;
    return p;
  };
  // f32 activations
  float* qwc      = (float*)alloc((size_t)256*512*4);
  float* qbc      = (float*)alloc(512*4);
  float* emb_raw  = (float*)alloc((size_t)BS*512*4);
  float* emb      = (float*)alloc((size_t)BS*512*4);
  float* kvt      = (float*)alloc((size_t)BS*512*4);
  float* kvn      = (float*)alloc((size_t)BS*512*4);
  float* kbuf     = (float*)alloc((size_t)BS*512*4);
  float* vbuf     = (float*)alloc((size_t)BS*512*4);
  float* act      = (float*)alloc((size_t)BS*512*4);
  float* aaB      = (float*)alloc((size_t)BS*256*4);
  float* baB      = (float*)alloc((size_t)BS*256*4);
  float* aoB      = (float*)alloc((size_t)BS*512*4);
  float* boB      = (float*)alloc((size_t)BS*512*4);
  float* sync_a   = (float*)alloc((size_t)BS*256*4);
  float* qh       = (float*)alloc((size_t)BS*512*4);
  float* attn_raw = (float*)alloc((size_t)BS*512*4);
  float* catb     = (float*)alloc((size_t)BS*1024*4);
  float* syn_y    = (float*)alloc((size_t)BS*1024*4);
  float* states[NTICK];
  for (int t = 0; t < NTICK; t++) states[t] = (float*)alloc((size_t)BS*512*4);
  bf16* syob[NTICK];
  for (int t = 0; t < NTICK; t++) syob[t] = (bf16*)alloc((size_t)BS*512*2);
  // split weights (bf16, transposed [N][K])
  bf16* kvT_h = (bf16*)alloc((size_t)512*512*2);
  bf16* kvT_l = (bf16*)alloc((size_t)512*512*2);
  bf16* wkT_h = (bf16*)alloc((size_t)512*512*2);
  bf16* wkT_l = (bf16*)alloc((size_t)512*512*2);
  bf16* wvT_h = (bf16*)alloc((size_t)512*512*2);
  bf16* wvT_l = (bf16*)alloc((size_t)512*512*2);
  bf16* owT_h = (bf16*)alloc((size_t)512*512*2);
  bf16* owT_l = (bf16*)alloc((size_t)512*512*2);
  bf16* wqT_h = (bf16*)alloc((size_t)512*512*2);
  bf16* wqT_l = (bf16*)alloc((size_t)512*512*2);
  bf16* synT_h = (bf16*)alloc((size_t)1024*1024*2);
  bf16* synT_l = (bf16*)alloc((size_t)1024*1024*2);
  bf16* qwcT_h = (bf16*)alloc((size_t)512*256*2);
  bf16* qwcT_l = (bf16*)alloc((size_t)512*256*2);
  bf16* WoT    = (bf16*)alloc((size_t)VOCAB*512*2);
  // entropy partials
  float* pm = (float*)alloc((size_t)BS*4*NBLK*4);
  float* pz = (float*)alloc((size_t)BS*4*NBLK*4);
  float* ps = (float*)alloc((size_t)BS*4*NBLK*4);

  float* preds = (float*)d_out;
  float* certs = (float*)d_out + (size_t)BS*VOCAB*NTICK;

  // ---- weight prep
  split_t<<<dim3(16,16), 256, 0, stream>>>(kv_w,  kvT_h, kvT_l, 512, 512);
  split_t<<<dim3(16,16), 256, 0, stream>>>(wk,    wkT_h, wkT_l, 512, 512);
  split_t<<<dim3(16,16), 256, 0, stream>>>(wv,    wvT_h, wvT_l, 512, 512);
  split_t<<<dim3(16,16), 256, 0, stream>>>(ow,    owT_h, owT_l, 512, 512);
  split_t<<<dim3(16,16), 256, 0, stream>>>(wq,    wqT_h, wqT_l, 512, 512);
  split_t<<<dim3(32,32), 256, 0, stream>>>(syn_w, synT_h, synT_l, 1024, 1024);
  split_t<<<dim3(VOCAB/32,16), 256, 0, stream>>>(out_w, WoT, nullptr, 512, VOCAB);

  // ---- pre
  embed_kernel<<<BS, 128, 0, stream>>>(x, tok, pos, emb_raw);
  ln512_kernel<<<BS, 256, 0, stream>>>(emb_raw, ln_emb_g, ln_emb_b, emb);
  gemm_x3<<<dim3(8,32), 64, 0, stream>>>(emb, kvT_h, kvT_l, kv_b, kvt, 512, 512, 512);
  ln512_kernel<<<BS, 256, 0, stream>>>(kvt, kv_ln_g, kv_ln_b, kvn);
  gemm_x3<<<dim3(8,32), 64, 0, stream>>>(kvn, wkT_h, wkT_l, bk, kbuf, 512, 512, 512);
  gemm_x3<<<dim3(8,32), 64, 0, stream>>>(kvn, wvT_h, wvT_l, bv, vbuf, 512, 512, 512);
  gemm_x3<<<dim3(8,16), 64, 0, stream>>>(q_w, wqT_h, wqT_l, nullptr, qwc, 512, 512, 512);
  split_t<<<dim3(16,8), 256, 0, stream>>>(qwc, qwcT_h, qwcT_l, 256, 512);
  qbc_kernel<<<8, 64, 0, stream>>>(q_b, wq, bq, qbc);
  act_init_kernel<<<(BS*NN)/256, 256, 0, stream>>>(start_act, act);

  // ---- ticks
  for (int t = 0; t < NTICK; t++){
    sync_kernel<<<(BS*NSA)/256, 256, 0, stream>>>(act, idx_al, idx_ar, decay_a,
        aaB, baB, sync_a, nullptr, NSA, t==0);
    gemm_x3<<<dim3(8,32), 64, 0, stream>>>(sync_a, qwcT_h, qwcT_l, qbc, qh, 256, 256, 512);
    attn_kernel<<<dim3(16, NHEAD, BATCH), 256, 0, stream>>>(qh, kbuf, vbuf, attn_raw);
    gemm_x3<<<dim3(8,32), 64, 0, stream>>>(attn_raw, owT_h, owT_l, ob, catb, 512, 512, 1024);
    cat_act_kernel<<<(BS*NN)/256, 256, 0, stream>>>(act, catb);
    gemm_x3<<<dim3(16,32), 64, 0, stream>>>(catb, synT_h, synT_l, syn_b, syn_y, 1024, 1024, 1024);
    glu_ln_kernel<<<BS, 256, 0, stream>>>(syn_y, syn_g, syn_beta, states[t]);
    nlm_kernel<<<dim3(NN, BATCH), 256, 0, stream>>>(start_trace,
        states[0], states[1], states[2], states[3],
        fc1_w, fc1_b, fc2_w, fc2_b, nlm_T, act, t);
    sync_kernel<<<(BS*NSO)/256, 256, 0, stream>>>(act, idx_ol, idx_or, decay_o,
        aoB, boB, nullptr, syob[t], NSO, t==0);
  }

  // ---- output projection (fused entropy partials) + finalize
  out_gemm2<<<dim3(32, NBLK), 256, 0, stream>>>(
      syob[0], syob[1], syob[2], syob[3], WoT, out_b, preds, pm, pz, ps);
  ent_final<<<BS*4, 64, 0, stream>>>(pm, pz, ps, certs);
}